// Round 17
// baseline (1020.981 us; speedup 1.0000x reference)
//
#include <hip/hip_runtime.h>
#include <cstdint>
#include <cstddef>

// Problem constants
#define BB 4
#define SS 4096
#define HH 1024
#define PP 10
#define LL 4106              // P + S
#define NTILES 129
#define CHUNKS_PB (NTILES * 4096)   // 16B-chunks per batch plane (= 528384)
#define TILE_ELEMS (4096 * 8)       // fp16 elems per tile in a plane
#define LOG2E 1.44269504088896f

typedef __attribute__((ext_vector_type(8))) _Float16 half8v;  // 4 VGPR MFMA frag
typedef __attribute__((ext_vector_type(4))) float float4v;

union hu16 { _Float16 h; unsigned short u; };

__device__ __forceinline__ half8v cvt8h(float4v f0, float4v f1) {
  half8v h;
  h[0] = (_Float16)f0[0]; h[1] = (_Float16)f0[1];
  h[2] = (_Float16)f0[2]; h[3] = (_Float16)f0[3];
  h[4] = (_Float16)f1[0]; h[5] = (_Float16)f1[1];
  h[6] = (_Float16)f1[2]; h[7] = (_Float16)f1[3];
  return h;
}
__device__ __forceinline__ unsigned pack2h(float a, float b) {
  hu16 x, y; x.h = (_Float16)a; y.h = (_Float16)b;
  return (unsigned)x.u | ((unsigned)y.u << 16);
}

// DPP lane permute within 16-lane rows (VALU pipe).
template<int C>
__device__ __forceinline__ float dppf(float x) {
  return __int_as_float(
      __builtin_amdgcn_update_dpp(0, __float_as_int(x), C, 0xF, 0xF, true));
}
__device__ __forceinline__ float row16_max(float x) {
  x = fmaxf(x, dppf<0xB1>(x));
  x = fmaxf(x, dppf<0x4E>(x));
  x = fmaxf(x, dppf<0x140>(x));
  x = fmaxf(x, dppf<0x141>(x));
  return x;
}
__device__ __forceinline__ float row16_sum(float x) {
  x += dppf<0xB1>(x);
  x += dppf<0x4E>(x);
  x += dppf<0x140>(x);
  x += dppf<0x141>(x);
  return x;
}

// raw barrier: drain own LDS ops, no vmcnt drain (keeps global loads in flight)
#define LGKM_BAR() do { \
  asm volatile("s_waitcnt lgkmcnt(0)" ::: "memory"); \
  __builtin_amdgcn_s_barrier(); \
  asm volatile("" ::: "memory"); } while (0)

// ---------- pre-kernels: fp16 planes in MFMA-fragment order (unchanged) ----------
__global__ __launch_bounds__(256) void conv_k(const float* __restrict__ prefix_k,
                                              const float* __restrict__ key,
                                              _Float16* __restrict__ kp) {
  const int b = blockIdx.y;
  const int id = blockIdx.x * 256 + threadIdx.x;       // < CHUNKS_PB
  const int li = id & 15, g = (id >> 4) & 3, ktp = (id >> 6) & 31,
            nt = (id >> 11) & 1, it = id >> 12;
  const int n = it * 32 + nt * 16 + li;
  const int d = ktp * 32 + g * 8;
  float4v f0 = {0.f, 0.f, 0.f, 0.f}, f1 = {0.f, 0.f, 0.f, 0.f};
  if (n < LL) {
    const float* src = (n < PP) ? prefix_k + (size_t)n * HH + d
                                : key + ((size_t)b * SS + (n - PP)) * HH + d;
    f0 = *(const float4v*)src; f1 = *(const float4v*)(src + 4);
  }
  *(half8v*)(kp + ((size_t)b * CHUNKS_PB + id) * 8) = cvt8h(f0, f1);
}

__global__ __launch_bounds__(256) void conv_v(const float* __restrict__ prefix_v,
                                              const float* __restrict__ value,
                                              _Float16* __restrict__ vp) {
  const int b = blockIdx.y;
  const int id = blockIdx.x * 256 + threadIdx.x;
  const int d = id & 1023, g = (id >> 10) & 3, it = id >> 12;
  const int nb = it * 32 + g * 8;
  half8v h;
  #pragma unroll
  for (int j = 0; j < 8; ++j) {
    int n = nb + j;
    float f = 0.f;
    if (n < LL)
      f = (n < PP) ? prefix_v[(size_t)n * HH + d]
                   : value[((size_t)b * SS + (n - PP)) * HH + d];
    h[j] = (_Float16)f;
  }
  *(half8v*)(vp + ((size_t)b * CHUNKS_PB + id) * 8) = h;
}

// ---------------- fused flash attention, v18: Mq=64 twin tiles, JIT K+V ----------------
// 256 blocks (1/CU), 8 waves, wave w owns D-slice [128w,128w+128) for BOTH
// 32-row tiles A and B. K AND V load JIT at use via 32-bit offsets (no kreg/
// vreg arrays): arch demand ~120 <= 128 cap -> no spill (v11 had kreg -> 152
// -> spilled). K/V bytes from L2 are shared by both tiles: L2 stream halves
// vs v13 (8.65 -> 4.3 GB). v11's verified pipeline/parities/LDS layout.
template<int PATH>
__global__ __launch_bounds__(512, 1) void attn_fused(
    const float* __restrict__ q,
    const float* __restrict__ key,
    const float* __restrict__ value,
    const float* __restrict__ prefix_k,
    const float* __restrict__ prefix_v,
    const _Float16* __restrict__ kp,
    const _Float16* __restrict__ vp,
    float* __restrict__ out)
{
  __shared__ __align__(16) float sbA0[8][32][33], sbA1[8][32][33];   // 33.8 KB each
  __shared__ __align__(16) float sbB0[8][32][33], sbB1[8][32][33];
  __shared__ __align__(16) unsigned short PlA0[32][40], PlA1[32][40];
  __shared__ __align__(16) unsigned short PlB0[32][40], PlB1[32][40];
  __shared__ float scA0[32], scA1[32], scB0[32], scB1[32];
  __shared__ float lA[32], lB[32];

  const int tid = threadIdx.x;
  const int w = tid >> 6, ln = tid & 63, g = ln >> 4, li = ln & 15;
  const int bid = blockIdx.x, xcd = bid & 7, b = xcd >> 1;
  const int qt = ((bid >> 3) << 1) | (xcd & 1);   // 0..63
  const int q0 = qt * 64;
  const int dbase = w * 128;

  // Q fragments fp16 for both tiles: A-layout row=li, k=g*8+j
  half8v qfA[2][4], qfB[2][4];
  #pragma unroll
  for (int mt = 0; mt < 2; ++mt)
    #pragma unroll
    for (int kt = 0; kt < 4; ++kt) {
      const float* pA = q + ((size_t)(b * SS + q0 + mt * 16 + li)) * HH + dbase + kt * 32 + g * 8;
      const float* pB = pA + (size_t)32 * HH;
      qfA[mt][kt] = cvt8h(*(const float4v*)pA, *(const float4v*)(pA + 4));
      qfB[mt][kt] = cvt8h(*(const float4v*)pB, *(const float4v*)(pB + 4));
    }

  float4v z4 = {0.f, 0.f, 0.f, 0.f};
  float4v oA[2][8], oB[2][8];
  #pragma unroll
  for (int mt = 0; mt < 2; ++mt)
    #pragma unroll
    for (int dt = 0; dt < 8; ++dt) { oA[mt][dt] = z4; oB[mt][dt] = z4; }
  float m_rA = -1e30f, l_rA = 0.f, m_rB = -1e30f, l_rB = 0.f;

  // 32-bit element offsets into the planes (saves VGPRs vs 64-bit pointers)
  const unsigned k_off = (unsigned)b * (CHUNKS_PB * 8u)
                         + (unsigned)(w * 256 + g * 16 + li) * 8u;
  const unsigned v_off = (unsigned)b * (CHUNKS_PB * 8u)
                         + ((unsigned)g * 1024u + (unsigned)(dbase + li)) * 8u;

  const int srow = w * 4 + (ln >> 4);     // slab row this lane handles in softmax
  const int c0 = (ln & 15) * 2;

  // QK for one tile into one named sbuf bank; K loaded JIT (shared by A/B
  // via L1/L2 — the two calls in a region use identical addresses)
  auto do_qk = [&](int i, const half8v (&qf)[2][4], float (*sb)[32][33])
      __attribute__((always_inline)) {
    float4v sacc[2][2];
    sacc[0][0] = z4; sacc[0][1] = z4; sacc[1][0] = z4; sacc[1][1] = z4;
    const unsigned ko = k_off + (unsigned)i * TILE_ELEMS;
    #pragma unroll
    for (int kt = 0; kt < 4; ++kt) {
      half8v kb[2];
      if constexpr (PATH == 0) {
        kb[0] = *(const half8v*)(kp + ko + kt * 512);
        kb[1] = *(const half8v*)(kp + ko + 16384 + kt * 512);
      } else {
        #pragma unroll
        for (int nt = 0; nt < 2; ++nt) {
          int n = i * 32 + nt * 16 + li;
          int nc = (n < LL) ? n : 0;
          const float* kpp = (nc < PP) ? (prefix_k + (size_t)nc * HH)
                                       : (key + ((size_t)b * SS + (nc - PP)) * HH);
          kpp += dbase + kt * 32 + g * 8;
          kb[nt] = cvt8h(*(const float4v*)kpp, *(const float4v*)(kpp + 4));
        }
      }
      #pragma unroll
      for (int mt = 0; mt < 2; ++mt)
        #pragma unroll
        for (int nt = 0; nt < 2; ++nt)
          sacc[mt][nt] = __builtin_amdgcn_mfma_f32_16x16x32_f16(qf[mt][kt], kb[nt], sacc[mt][nt], 0, 0, 0);
    }
    // C/D: row = g*4+r, col = li
    #pragma unroll
    for (int mt = 0; mt < 2; ++mt)
      #pragma unroll
      for (int nt = 0; nt < 2; ++nt)
        #pragma unroll
        for (int r = 0; r < 4; ++r)
          sb[w][mt * 16 + g * 4 + r][nt * 16 + li] = sacc[mt][nt][r];
  };

  auto do_sm = [&](int t, const float (*sb)[32][33],
                   unsigned short (*plw)[40], float* scw, float& m_r, float& l_r)
      __attribute__((always_inline)) {
    float s0 = 0.f, s1 = 0.f;
    #pragma unroll
    for (int bw = 0; bw < 8; ++bw) {
      float2 tv = *(const float2*)&sb[bw][srow][c0];
      s0 += tv.x; s1 += tv.y;
    }
    if constexpr (PATH == 1) {
      if (t * 32 + c0 >= LL)     s0 = -1e30f;
      if (t * 32 + c0 + 1 >= LL) s1 = -1e30f;
    }
    const float mx = row16_max(fmaxf(s0, s1));
    const float m_new = fmaxf(m_r, mx);
    const float scp = exp2f((m_r - m_new) * LOG2E);
    const float p0 = exp2f((s0 - m_new) * LOG2E);
    const float p1 = exp2f((s1 - m_new) * LOG2E);
    const float ts = row16_sum(p0 + p1);
    l_r = l_r * scp + ts;
    m_r = m_new;
    *(unsigned*)&plw[srow][c0] = pack2h(p0, p1);
    if ((ln & 15) == 0) scw[srow] = scp;
  };

  // PV for both tiles; V loaded JIT (8 x 16B, shared by A and B)
  auto do_pv2 = [&](int t) __attribute__((always_inline)) {
    const unsigned short (*plrA)[40] = (t & 1) ? PlA1 : PlA0;
    const unsigned short (*plrB)[40] = (t & 1) ? PlB1 : PlB0;
    const float* scrA = (t & 1) ? scA1 : scA0;
    const float* scrB = (t & 1) ? scB1 : scB0;
    float sccA[2][4], sccB[2][4];
    #pragma unroll
    for (int mt = 0; mt < 2; ++mt)
      #pragma unroll
      for (int r = 0; r < 4; ++r) {
        sccA[mt][r] = scrA[mt * 16 + g * 4 + r];
        sccB[mt][r] = scrB[mt * 16 + g * 4 + r];
      }
    #pragma unroll
    for (int mt = 0; mt < 2; ++mt)
      #pragma unroll
      for (int dt = 0; dt < 8; ++dt)
        #pragma unroll
        for (int r = 0; r < 4; ++r) {
          oA[mt][dt][r] *= sccA[mt][r];
          oB[mt][dt][r] *= sccB[mt][r];
        }
    half8v paA0 = *(const half8v*)&plrA[li][g * 8];
    half8v paA1 = *(const half8v*)&plrA[16 + li][g * 8];
    half8v paB0 = *(const half8v*)&plrB[li][g * 8];
    half8v paB1 = *(const half8v*)&plrB[16 + li][g * 8];
    const unsigned vo = v_off + (unsigned)t * TILE_ELEMS;
    #pragma unroll
    for (int dt = 0; dt < 8; ++dt) {
      half8v vb;
      if constexpr (PATH == 0) {
        vb = *(const half8v*)(vp + vo + dt * 128);
      } else {
        const int d = dbase + dt * 16 + li;
        #pragma unroll
        for (int j = 0; j < 8; ++j) {
          int n = t * 32 + g * 8 + j;
          int nc = (n < LL) ? n : 0;    // clamped rows have P==0
          float f = (nc < PP) ? prefix_v[(size_t)nc * HH + d]
                              : value[((size_t)b * SS + (nc - PP)) * HH + d];
          vb[j] = (_Float16)f;
        }
      }
      oA[0][dt] = __builtin_amdgcn_mfma_f32_16x16x32_f16(paA0, vb, oA[0][dt], 0, 0, 0);
      oA[1][dt] = __builtin_amdgcn_mfma_f32_16x16x32_f16(paA1, vb, oA[1][dt], 0, 0, 0);
      oB[0][dt] = __builtin_amdgcn_mfma_f32_16x16x32_f16(paB0, vb, oB[0][dt], 0, 0, 0);
      oB[1][dt] = __builtin_amdgcn_mfma_f32_16x16x32_f16(paB1, vb, oB[1][dt], 0, 0, 0);
    }
  };

  // ---- pipeline: prologue / steady (x2 unrolled) / epilogue (v11's shape) ----
  // parity: qk(i)->sb*(i&1); sm(t): sb*(t&1) -> Pl*(t&1)/sc*(t&1); pv(t): Pl*(t&1).
  do_qk(0, qfA, sbA0); do_qk(0, qfB, sbB0);
  LGKM_BAR();
  do_qk(1, qfA, sbA1); do_qk(1, qfB, sbB1);
  do_sm(0, sbA0, PlA0, scA0, m_rA, l_rA);
  do_sm(0, sbB0, PlB0, scB0, m_rB, l_rB);
  LGKM_BAR();
  int i = 2;
  for (; i + 1 < NTILES; i += 2) {
    // even iter i
    do_qk(i, qfA, sbA0); do_qk(i, qfB, sbB0);
    do_pv2(i - 2);
    do_sm(i - 1, sbA1, PlA1, scA1, m_rA, l_rA);
    do_sm(i - 1, sbB1, PlB1, scB1, m_rB, l_rB);
    LGKM_BAR();
    // odd iter i+1
    do_qk(i + 1, qfA, sbA1); do_qk(i + 1, qfB, sbB1);
    do_pv2(i - 1);
    do_sm(i, sbA0, PlA0, scA0, m_rA, l_rA);
    do_sm(i, sbB0, PlB0, scB0, m_rB, l_rB);
    LGKM_BAR();
  }
  // tail steady iter i = NTILES-1 = 128 (even bank)
  do_qk(NTILES - 1, qfA, sbA0); do_qk(NTILES - 1, qfB, sbB0);
  do_pv2(NTILES - 3);
  do_sm(NTILES - 2, sbA1, PlA1, scA1, m_rA, l_rA);
  do_sm(NTILES - 2, sbB1, PlB1, scB1, m_rB, l_rB);
  LGKM_BAR();
  // epilogue
  do_pv2(NTILES - 2);
  do_sm(NTILES - 1, sbA0, PlA0, scA0, m_rA, l_rA);
  do_sm(NTILES - 1, sbB0, PlB0, scB0, m_rB, l_rB);
  LGKM_BAR();
  do_pv2(NTILES - 1);

  // ---- finalize ----
  if ((ln & 15) == 0) { lA[srow] = l_rA; lB[srow] = l_rB; }
  LGKM_BAR();
  float ilA[2][4], ilB[2][4];
  #pragma unroll
  for (int mt = 0; mt < 2; ++mt)
    #pragma unroll
    for (int r = 0; r < 4; ++r) {
      ilA[mt][r] = 1.0f / lA[mt * 16 + g * 4 + r];
      ilB[mt][r] = 1.0f / lB[mt * 16 + g * 4 + r];
    }
  #pragma unroll
  for (int mt = 0; mt < 2; ++mt)
    #pragma unroll
    for (int dt = 0; dt < 8; ++dt)
      #pragma unroll
      for (int r = 0; r < 4; ++r) {
        const size_t rowA = (size_t)(b * SS + q0 + mt * 16 + g * 4 + r);
        out[rowA * HH + dbase + dt * 16 + li] = oA[mt][dt][r] * ilA[mt][r];
        out[(rowA + 32) * HH + dbase + dt * 16 + li] = oB[mt][dt][r] * ilB[mt][r];
      }
}

extern "C" void kernel_launch(void* const* d_in, const int* in_sizes, int n_in,
                              void* d_out, int out_size, void* d_ws, size_t ws_size,
                              hipStream_t stream) {
  const float* q        = (const float*)d_in[0];
  const float* key      = (const float*)d_in[1];
  const float* value    = (const float*)d_in[2];
  const float* prefix_k = (const float*)d_in[3];
  const float* prefix_v = (const float*)d_in[4];
  float* out = (float*)d_out;

  const size_t PLANE = (size_t)BB * CHUNKS_PB * 8;              // fp16 elems per plane
  const size_t NEED  = 2 * PLANE * sizeof(unsigned short);      // 67.6 MB

  if (ws_size >= NEED) {
    _Float16* kp = (_Float16*)d_ws;
    _Float16* vp = kp + PLANE;
    conv_k<<<dim3(CHUNKS_PB / 256, BB), 256, 0, stream>>>(prefix_k, key, kp);
    conv_v<<<dim3(CHUNKS_PB / 256, BB), 256, 0, stream>>>(prefix_v, value, vp);
    attn_fused<0><<<256, 512, 0, stream>>>(q, key, value, prefix_k, prefix_v, kp, vp, out);
  } else {
    attn_fused<1><<<256, 512, 0, stream>>>(q, key, value, prefix_k, prefix_v,
                                           nullptr, nullptr, out);
  }
}